// Round 2
// baseline (6871.264 us; speedup 1.0000x reference)
//
#include <hip/hip_runtime.h>
#include <math.h>

// Problem constants
#define BB   64
#define SS   256
#define ED   300
#define HH   512
#define G3   1536   // 3*H (one direction)
#define ATT_ 256
#define BS_  16384  // BB*SS

// ---------------------------------------------------------------------------
// K1: embedding gather + max-norm renorm.  one block per (b,s) row, 128 thr
// ---------------------------------------------------------------------------
__global__ void k_embed(const int* __restrict__ x, const float* __restrict__ emb,
                        float* __restrict__ e) {
    int row = blockIdx.x;
    int tok = x[row];
    const float* src = emb + (size_t)tok * ED;
    float* dst = e + (size_t)row * ED;
    int tid = threadIdx.x;  // 128
    float v[3];
    float ss = 0.f;
#pragma unroll
    for (int i = 0; i < 3; ++i) {
        int k = tid + i * 128;
        float t = (k < ED) ? src[k] : 0.f;
        v[i] = t;
        ss += t * t;
    }
    for (int off = 32; off > 0; off >>= 1) ss += __shfl_xor(ss, off, 64);
    __shared__ float red[2];
    if ((tid & 63) == 0) red[tid >> 6] = ss;
    __syncthreads();
    float nrm = sqrtf(red[0] + red[1]);
    float scale = fminf(1.0f, 5.0f / (nrm + 1e-7f));
#pragma unroll
    for (int i = 0; i < 3; ++i) {
        int k = tid + i * 128;
        if (k < ED) dst[k] = v[i] * scale;
    }
}

// ---------------------------------------------------------------------------
// K_prep_dir: Wt[300][1536] = Wih_dir^T, bc[1536] = bih_dir
// ---------------------------------------------------------------------------
__global__ void k_prep_dir(const float* __restrict__ Wih, const float* __restrict__ bih,
                           float* __restrict__ Wt, float* __restrict__ bc) {
    int idx = blockIdx.x * blockDim.x + threadIdx.x;
    int stride = gridDim.x * blockDim.x;
    for (int i = idx; i < ED * G3; i += stride) {
        int k = i / G3, n = i % G3;
        Wt[i] = Wih[(size_t)n * ED + k];
    }
    for (int i = idx; i < G3; i += stride) bc[i] = bih[i];
}

// K_prep_w1: W1at[1024][256] = transpose of W1[:, :1024]
__global__ void k_prep_w1(const float* __restrict__ W1, float* __restrict__ W1at) {
    int idx = blockIdx.x * blockDim.x + threadIdx.x;
    int stride = gridDim.x * blockDim.x;
    for (int i = idx; i < 1024 * ATT_; i += stride) {
        int k = i / ATT_, n = i % ATT_;
        W1at[i] = W1[(size_t)n * 2048 + k];
    }
}

// ---------------------------------------------------------------------------
// Generic fp32 tiled GEMM: C[M,N] = A[M,K](row-major) * B[K,N](row-major)
// 64x64 tile, 256 threads, 4x4 per thread.  Optional batching via z.
// EPI: 0 = none, 1 = +bias[n], 2 = tanh(acc + bias2[(row>>8)*256 + n])
// ---------------------------------------------------------------------------
template <int KT, int EPI>
__global__ void __launch_bounds__(256) k_gemm(
    const float* __restrict__ A, int lda, long strideA,
    const float* __restrict__ Bm, int ldb, long strideB,
    float* __restrict__ C, int ldc, long strideC,
    int M, int N, int K,
    const float* __restrict__ bias, const float* __restrict__ bias2) {
    __shared__ float As[64][KT];
    __shared__ float Bs[KT][64];
    const int tid = threadIdx.x;
    const int tx = tid & 15, ty = tid >> 4;
    const int mbase = blockIdx.y * 64, nbase = blockIdx.x * 64;
    const float* Ab = A + (long)blockIdx.z * strideA;
    const float* Bb = Bm + (long)blockIdx.z * strideB;
    float* Cb = C + (long)blockIdx.z * strideC;
    float acc[4][4] = {};
    for (int k0 = 0; k0 < K; k0 += KT) {
        for (int i = tid; i < 64 * KT; i += 256) {
            int r = i / KT, c = i % KT;
            As[r][c] = Ab[(size_t)(mbase + r) * lda + k0 + c];
        }
        for (int i = tid; i < KT * 64; i += 256) {
            int kk = i >> 6, n = i & 63;
            Bs[kk][n] = Bb[(size_t)(k0 + kk) * ldb + nbase + n];
        }
        __syncthreads();
#pragma unroll
        for (int kk = 0; kk < KT; ++kk) {
            float a0 = As[ty * 4 + 0][kk], a1 = As[ty * 4 + 1][kk];
            float a2 = As[ty * 4 + 2][kk], a3 = As[ty * 4 + 3][kk];
            float b0 = Bs[kk][tx * 4 + 0], b1 = Bs[kk][tx * 4 + 1];
            float b2 = Bs[kk][tx * 4 + 2], b3 = Bs[kk][tx * 4 + 3];
            acc[0][0] += a0 * b0; acc[0][1] += a0 * b1; acc[0][2] += a0 * b2; acc[0][3] += a0 * b3;
            acc[1][0] += a1 * b0; acc[1][1] += a1 * b1; acc[1][2] += a1 * b2; acc[1][3] += a1 * b3;
            acc[2][0] += a2 * b0; acc[2][1] += a2 * b1; acc[2][2] += a2 * b2; acc[2][3] += a2 * b3;
            acc[3][0] += a3 * b0; acc[3][1] += a3 * b1; acc[3][2] += a3 * b2; acc[3][3] += a3 * b3;
        }
        __syncthreads();
    }
#pragma unroll
    for (int i = 0; i < 4; ++i) {
        int row = mbase + ty * 4 + i;
#pragma unroll
        for (int j = 0; j < 4; ++j) {
            int col = nbase + tx * 4 + j;
            float v = acc[i][j];
            if (EPI == 1) v += bias[col];
            if (EPI == 2) v = tanhf(v + bias2[(size_t)(row >> 8) * ATT_ + col]);
            Cb[(size_t)row * ldc + col] = v;
        }
    }
}

// ---------------------------------------------------------------------------
// GRU step, one direction, one launch per timestep (no grid sync needed).
// 256 blocks x 2 units each; 256 threads = (b:64) x (unit_local:2) x (khalf:2).
// Each thread computes half (K=256) of the 3 gate dots; __shfl_xor(1) combines.
// ---------------------------------------------------------------------------
__device__ __forceinline__ float sigmoidf_(float v) { return 1.f / (1.f + expf(-v)); }

__global__ void __launch_bounds__(256)
k_gru_step2(const float* __restrict__ xw,   // [B,S,1536] for this dir
            const float* __restrict__ Whh, const float* __restrict__ bhh,
            float* __restrict__ h_all, int i, int dir) {
    const int bu = blockIdx.x;          // 0..255
    const int tid = threadIdx.x;
    const int b  = tid >> 2;            // 0..63
    const int t2 = tid & 3;
    const int ul = t2 >> 1;             // unit within block: 0..1
    const int kh = t2 & 1;              // K-half: 0..1
    const int ug = bu * 2 + ul;         // global unit 0..511
    __shared__ float Ws[3][2][512];     // 12 KB
    __shared__ float bsh[3][2];
    for (int t = tid; t < 3072; t += 256) {
        int g = t >> 10, u = (t >> 9) & 1, k = t & 511;
        Ws[g][u][k] = Whh[(size_t)(g * 512 + bu * 2 + u) * 512 + k];
    }
    if (tid < 6) bsh[tid >> 1][tid & 1] = bhh[(tid >> 1) * 512 + bu * 2 + (tid & 1)];
    __syncthreads();
    const int pos = dir ? (255 - i) : i;
    float hr = 0.f, hz = 0.f, hn = 0.f;
    float hold = 0.f;
    if (i > 0) {
        const int ppos = dir ? (pos + 1) : (pos - 1);
        const float* hrow = h_all + ((size_t)b * 256 + ppos) * 1024 + dir * 512;
        hold = hrow[ug];
        const float4* __restrict__ hp = (const float4*)(hrow + kh * 256);
        const float4* __restrict__ w0 = (const float4*)(&Ws[0][ul][kh * 256]);
        const float4* __restrict__ w1 = (const float4*)(&Ws[1][ul][kh * 256]);
        const float4* __restrict__ w2 = (const float4*)(&Ws[2][ul][kh * 256]);
#pragma unroll 8
        for (int k4 = 0; k4 < 64; ++k4) {
            float4 h4 = hp[k4];
            float4 a = w0[k4]; hr += h4.x * a.x + h4.y * a.y + h4.z * a.z + h4.w * a.w;
            float4 c = w1[k4]; hz += h4.x * c.x + h4.y * c.y + h4.z * c.z + h4.w * c.w;
            float4 d = w2[k4]; hn += h4.x * d.x + h4.y * d.y + h4.z * d.z + h4.w * d.w;
        }
    }
    hr += __shfl_xor(hr, 1, 64);
    hz += __shfl_xor(hz, 1, 64);
    hn += __shfl_xor(hn, 1, 64);
    const float* __restrict__ xrow = xw + ((size_t)b * 256 + pos) * 1536;
    float xr = xrow[ug], xz = xrow[512 + ug], xn = xrow[1024 + ug];
    float r = sigmoidf_(xr + bsh[0][ul] + hr);
    float z = sigmoidf_(xz + bsh[1][ul] + hz);
    float n = tanhf(xn + r * (bsh[2][ul] + hn));
    float hcur = (1.f - z) * n + z * hold;
    if (kh == 0)
        h_all[((size_t)b * 256 + pos) * 1024 + dir * 512 + ug] = hcur;
}

// ---------------------------------------------------------------------------
// K4: masked mean over target span -> target[b, 1024]
// ---------------------------------------------------------------------------
__global__ void k_target(const float* __restrict__ h_all, const int* __restrict__ ts,
                         const int* __restrict__ te, float* __restrict__ target) {
    int b = blockIdx.x;
    int tid = threadIdx.x;  // 256
    int s0 = ts[b], s1 = te[b];
    float inv = 1.f / (float)(s1 - s0 + 1);
    for (int d = tid; d < 1024; d += 256) {
        float acc = 0.f;
        for (int s = s0; s <= s1; ++s) acc += h_all[((size_t)b * 256 + s) * 1024 + d];
        target[(size_t)b * 1024 + d] = acc * inv;
    }
}

// ---------------------------------------------------------------------------
// K4b: tmp2[b,a] = b1[a] + target[b,:] . W1[a, 1024:2048]
// ---------------------------------------------------------------------------
__global__ void k_tmp2(const float* __restrict__ target, const float* __restrict__ W1,
                       const float* __restrict__ b1, float* __restrict__ tmp2) {
    int b = blockIdx.x;
    int a = threadIdx.x;  // 256
    __shared__ float tg[1024];
    for (int d = a; d < 1024; d += 256) tg[d] = target[(size_t)b * 1024 + d];
    __syncthreads();
    const float4* wrow = (const float4*)(W1 + (size_t)a * 2048 + 1024);
    const float4* tg4 = (const float4*)tg;
    float acc = b1[a];
    for (int k = 0; k < 256; ++k) {
        float4 w = wrow[k], t = tg4[k];
        acc += w.x * t.x + w.y * t.y + w.z * t.z + w.w * t.w;
    }
    tmp2[(size_t)b * ATT_ + a] = acc;
}

// ---------------------------------------------------------------------------
// transpose o[b][s][a] -> ot[b][a][s]
// ---------------------------------------------------------------------------
__global__ void k_transpose_o(const float* __restrict__ o, float* __restrict__ ot) {
    int b = blockIdx.z;
    __shared__ float t[32][33];
    int a0 = blockIdx.x * 32, s0 = blockIdx.y * 32;
    int tx = threadIdx.x & 31, ty = threadIdx.x >> 5;  // 32x8
    for (int i = ty; i < 32; i += 8)
        t[i][tx] = o[((size_t)b * 256 + s0 + i) * 256 + a0 + tx];
    __syncthreads();
    for (int i = ty; i < 32; i += 8)
        ot[((size_t)b * 256 + a0 + i) * 256 + s0 + tx] = t[tx][i];
}

// ---------------------------------------------------------------------------
// softmax over last axis, in place.  one block per (b,k) row of 256.
// ---------------------------------------------------------------------------
__global__ void k_softmax(float* __restrict__ beta) {
    int row = blockIdx.x;
    float* p = beta + (size_t)row * 256;
    int tid = threadIdx.x;  // 256
    float v = p[tid];
    float m = v;
    for (int off = 32; off > 0; off >>= 1) m = fmaxf(m, __shfl_xor(m, off, 64));
    __shared__ float red[4];
    if ((tid & 63) == 0) red[tid >> 6] = m;
    __syncthreads();
    m = fmaxf(fmaxf(red[0], red[1]), fmaxf(red[2], red[3]));
    float e = expf(v - m);
    float ssum = e;
    for (int off = 32; off > 0; off >>= 1) ssum += __shfl_xor(ssum, off, 64);
    __shared__ float red2[4];
    if ((tid & 63) == 0) red2[tid >> 6] = ssum;
    __syncthreads();
    float tot = red2[0] + red2[1] + red2[2] + red2[3];
    p[tid] = e / tot;
}

// ---------------------------------------------------------------------------
// final: out[row, 0:3] = result[row,:] . W2[l,:] + b2[l]
// ---------------------------------------------------------------------------
__global__ void k_final(const float* __restrict__ result, const float* __restrict__ W2,
                        const float* __restrict__ b2, float* __restrict__ out) {
    int row = blockIdx.x;
    int tid = threadIdx.x;  // 256
    const float* r = result + (size_t)row * 1024;
    float a0 = 0.f, a1 = 0.f, a2 = 0.f;
    for (int h = tid; h < 1024; h += 256) {
        float rv = r[h];
        a0 += rv * W2[h];
        a1 += rv * W2[1024 + h];
        a2 += rv * W2[2048 + h];
    }
    for (int off = 32; off > 0; off >>= 1) {
        a0 += __shfl_xor(a0, off, 64);
        a1 += __shfl_xor(a1, off, 64);
        a2 += __shfl_xor(a2, off, 64);
    }
    __shared__ float red[4][3];
    if ((tid & 63) == 0) {
        red[tid >> 6][0] = a0; red[tid >> 6][1] = a1; red[tid >> 6][2] = a2;
    }
    __syncthreads();
    if (tid < 3) {
        float s = red[0][tid] + red[1][tid] + red[2][tid] + red[3][tid];
        out[(size_t)row * 3 + tid] = s + b2[tid];
    }
}

// ---------------------------------------------------------------------------
extern "C" void kernel_launch(void* const* d_in, const int* in_sizes, int n_in,
                              void* d_out, int out_size, void* d_ws, size_t ws_size,
                              hipStream_t stream) {
    const int*   x      = (const int*)d_in[0];
    const int*   tstart = (const int*)d_in[1];
    const int*   tend   = (const int*)d_in[2];
    const float* emb    = (const float*)d_in[3];
    const float* Wihf   = (const float*)d_in[4];
    const float* Whhf   = (const float*)d_in[5];
    const float* bihf   = (const float*)d_in[6];
    const float* bhhf   = (const float*)d_in[7];
    const float* Wihb   = (const float*)d_in[8];
    const float* Whhb   = (const float*)d_in[9];
    const float* bihb   = (const float*)d_in[10];
    const float* bhhb   = (const float*)d_in[11];
    const float* W1     = (const float*)d_in[12];
    const float* b1     = (const float*)d_in[13];
    const float* u      = (const float*)d_in[14];
    const float* W2     = (const float*)d_in[15];
    const float* b2     = (const float*)d_in[16];
    float* out = (float*)d_out;
    float* ws = (float*)d_ws;

    // workspace layout (floats).  total = 47,664,640 floats = 190.7 MB
    float* h_p    = ws;                       // 16,777,216
    float* e_p    = h_p + 16777216;           // 4,915,200  (dead after 2nd xw GEMM)
    float* xw_p   = e_p + 4915200;            // 25,165,824 (per-dir; dead after GRUs)
    float* Wt_p   = xw_p + 25165824;          // 460,800
    float* bc_p   = Wt_p + 460800;            // 1,536
    float* W1at_p = bc_p + 1536;              // 262,144
    float* tg_p   = W1at_p + 262144;          // 65,536
    float* t2_p   = tg_p + 65536;             // 16,384
    // aliases into dead regions (after both GRU passes):
    float* o_p    = e_p;                      // 4,194,304 <= 4,915,200
    float* res_p  = xw_p;                     // 16,777,216
    float* ot_p   = xw_p + 16777216;          // 4,194,304
    float* beta_p = xw_p + 20971520;          // 4,194,304 (ends exactly at region end)

    if (ws_size < (size_t)47664640 * 4) return;  // refuse to overflow scratch

    // 1. embedding + renorm
    k_embed<<<BS_, 128, 0, stream>>>(x, emb, e_p);
    // 2. W1 transpose (once)
    k_prep_w1<<<256, 256, 0, stream>>>(W1, W1at_p);
    // 3. per-direction: input proj GEMM, then 256 GRU step launches
    for (int dir = 0; dir < 2; ++dir) {
        const float* Wih = dir ? Wihb : Wihf;
        const float* bih = dir ? bihb : bihf;
        const float* Whh = dir ? Whhb : Whhf;
        const float* bhh = dir ? bhhb : bhhf;
        k_prep_dir<<<512, 256, 0, stream>>>(Wih, bih, Wt_p, bc_p);
        k_gemm<20, 1><<<dim3(24, 256, 1), 256, 0, stream>>>(
            e_p, ED, 0, Wt_p, G3, 0, xw_p, G3, 0, BS_, G3, ED, bc_p, nullptr);
        for (int i = 0; i < 256; ++i)
            k_gru_step2<<<256, 256, 0, stream>>>(xw_p, Whh, bhh, h_p, i, dir);
    }
    // 4. target span mean
    k_target<<<BB, 256, 0, stream>>>(h_p, tstart, tend, tg_p);
    // 5. tmp2[b,a] = b1 + target . W1[:,1024:]
    k_tmp2<<<BB, 256, 0, stream>>>(tg_p, W1, b1, t2_p);
    // 6. o = tanh(h @ W1a^T + tmp2)   [16384, 256]
    k_gemm<16, 2><<<dim3(4, 256, 1), 256, 0, stream>>>(
        h_p, 1024, 0, W1at_p, ATT_, 0, o_p, ATT_, 0, BS_, ATT_, 1024, nullptr, t2_p);
    // 7. transpose o -> ot[b][a][s]
    k_transpose_o<<<dim3(8, 8, BB), 256, 0, stream>>>(o_p, ot_p);
    // 8. beta[b][k][s] = u @ ot[b]
    k_gemm<16, 0><<<dim3(4, 4, BB), 256, 0, stream>>>(
        u, ATT_, 0, ot_p, ATT_, 65536, beta_p, ATT_, 65536, ATT_, ATT_, ATT_, nullptr, nullptr);
    // 9. softmax over s (in place)
    k_softmax<<<BS_, 256, 0, stream>>>(beta_p);
    // 10. result[b][k][h] = alfa[b] @ h[b]
    k_gemm<16, 0><<<dim3(16, 4, BB), 256, 0, stream>>>(
        beta_p, ATT_, 65536, h_p, 1024, 262144, res_p, 1024, 262144,
        ATT_, 1024, ATT_, nullptr, nullptr);
    // 11. final linear
    k_final<<<BS_, 256, 0, stream>>>(res_p, W2, b2, out);
}